// Round 5
// baseline (683.132 us; speedup 1.0000x reference)
//
#include <hip/hip_runtime.h>
#include <hip/hip_bf16.h>
#include <math.h>

#define BB 8
#define SS 1024
#define EE 256
#define HH 8
#define DKK 32
#define LL 4
#define FF 1024
#define NQQ 256
#define CC 10

typedef __attribute__((ext_vector_type(8))) short short8;
typedef __attribute__((ext_vector_type(4))) short s16x4;
typedef __attribute__((ext_vector_type(4))) float f32x4;

static __device__ __forceinline__ f32x4 mfma16(short8 a, short8 b, f32x4 c) {
    return __builtin_amdgcn_mfma_f32_16x16x32_bf16(a, b, c, 0, 0, 0);
}
static __device__ __forceinline__ short f2bf(float f) {
    __hip_bfloat16 h = __float2bfloat16(f);
    return *reinterpret_cast<short*>(&h);
}

// ---------------------------------------------------------------------------
// Kernel 1: x[b,s,e] = emb[tokens[b,s], e] + pos_encoding(s, e)  (fp32, exact)
// ---------------------------------------------------------------------------
__global__ void k_embed(const int* __restrict__ tokens,
                        const float* __restrict__ emb,
                        float* __restrict__ x) {
    int bs = blockIdx.x;
    int e  = threadIdx.x;
    int s  = bs & (SS - 1);
    int tok = tokens[bs];
    int i2 = e >> 1;
    float div = expf(-(float)(2 * i2) * (logf(10000.0f) / (float)EE));
    float ang = (float)s * div;
    float pe = (e & 1) ? cosf(ang) : sinf(ang);
    x[bs * EE + e] = emb[tok * EE + e] + pe;
}

// ---------------------------------------------------------------------------
// Prep: transpose+convert weights to bf16 (W1T, W2T, WcT). Unchanged.
// ---------------------------------------------------------------------------
__global__ __launch_bounds__(256) void k_trall(
        const float* __restrict__ W1, const float* __restrict__ W2,
        const float* __restrict__ Wc,
        short* __restrict__ W1T, short* __restrict__ W2T, short* __restrict__ WcT) {
    int bid = blockIdx.x;
    int lyr = bid / 576, rem = bid % 576;
    const float* in; short* out; int R, C, tile;
    if (rem < 256)      { in = W1 + (size_t)lyr*NQQ*FF; out = W1T + (size_t)lyr*FF*NQQ; R = NQQ; C = FF;  tile = rem; }
    else if (rem < 512) { in = W2 + (size_t)lyr*FF*EE;  out = W2T + (size_t)lyr*EE*FF;  R = FF;  C = EE;  tile = rem - 256; }
    else                { in = Wc + (size_t)lyr*EE*EE;  out = WcT + (size_t)lyr*EE*EE;  R = EE;  C = EE;  tile = rem - 512; }
    int tiles_c = C >> 5;
    int tc = tile % tiles_c, tr = tile / tiles_c;
    __shared__ float tl[32][33];
    int t = threadIdx.x;
    int rr = t >> 5, cc = t & 31;
    #pragma unroll
    for (int i = 0; i < 4; ++i)
        tl[rr + i*8][cc] = in[(size_t)(tr*32 + rr + i*8) * C + tc*32 + cc];
    __syncthreads();
    int ro = t >> 3, co = (t & 7) * 4;
    s16x4 v;
    v[0] = f2bf(tl[co + 0][ro]);
    v[1] = f2bf(tl[co + 1][ro]);
    v[2] = f2bf(tl[co + 2][ro]);
    v[3] = f2bf(tl[co + 3][ro]);
    *(s16x4*)(out + (size_t)(tc*32 + ro) * R + tr*32 + co) = v;
}

// ---------------------------------------------------------------------------
// Kernel 2: quantum projection -> p (bf16) and p^T (bf16). Unchanged.
// ---------------------------------------------------------------------------
__global__ __launch_bounds__(256) void k_qproj2(
        const float* __restrict__ x, const float* __restrict__ theta,
        short* __restrict__ pbf, short* __restrict__ pbfT) {
    int idx = blockIdx.x * 256 + threadIdx.x;
    int h  = idx & (HH - 1);
    int bs = idx >> 3;
    int b  = bs >> 10, s = bs & (SS - 1);
    const float* xr = x + (size_t)bs * EE + h * DKK;
    const float* th = theta + h * DKK;
    float v[DKK];
    float cum = __cosf(xr[0] + th[0]);
    float prod1 = 1.0f;
    #pragma unroll
    for (int j = 1; j < DKK; ++j) {
        float c = __cosf(xr[j] + th[j]);
        cum *= c;
        prod1 *= c;
        v[j] = cum;
    }
    v[0] = prod1;
    short* pr = pbf + (size_t)bs * EE + h * DKK;
    #pragma unroll
    for (int j = 0; j < DKK; j += 2) {
        unsigned u = (unsigned)(unsigned short)f2bf(v[j]) |
                     ((unsigned)(unsigned short)f2bf(v[j + 1]) << 16);
        *(unsigned*)(pr + j) = u;
    }
    short* pT = pbfT + ((size_t)b * EE + h * DKK) * SS + s;
    #pragma unroll
    for (int j = 0; j < DKK; ++j)
        pT[(size_t)j * SS] = f2bf(v[j]);
}

// ---------------------------------------------------------------------------
// Kernel 3: flash attention, MFMA bf16, KV-split over 4 waves. Unchanged.
// ---------------------------------------------------------------------------
__global__ __launch_bounds__(256) void k_attn4(const short* __restrict__ pbf,
                                               const short* __restrict__ pbfT,
                                               short* __restrict__ ybf) {
    const int b   = blockIdx.x >> 6;
    const int qt  = blockIdx.x & 63;
    const int tid = threadIdx.x;
    const int w   = tid >> 6;
    const int l   = tid & 63;
    const int lr  = l & 15, lg = l >> 4;
    const int q0  = qt * 16;
    const short* pb  = pbf  + (size_t)b * SS * EE;
    const short* pbT = pbfT + (size_t)b * EE * SS;

    __shared__ float accL[4][16][264];
    __shared__ float mL[4][16];
    __shared__ float lsL[4][16];
    __shared__ short wlds[4][16 * 40];

    short8 qf[8];
    #pragma unroll
    for (int kg = 0; kg < 8; ++kg)
        qf[kg] = *(const short8*)(pb + (size_t)(q0 + lr) * EE + kg * 32 + lg * 8);

    f32x4 acc[16];
    #pragma unroll
    for (int i = 0; i < 16; ++i) acc[i] = f32x4{0.f, 0.f, 0.f, 0.f};
    float m[4]  = {-1e30f, -1e30f, -1e30f, -1e30f};
    float ls[4] = {0.f, 0.f, 0.f, 0.f};
    const float scale = 0.17677669529663687f;   // 1/sqrt(32)
    short* wl = wlds[w];

    for (int i = 0; i < 8; ++i) {
        const int kt = w + 4 * i;
        short8 sb0[8], sb1[8];
        #pragma unroll
        for (int kg = 0; kg < 8; ++kg) {
            sb0[kg] = *(const short8*)(pb + (size_t)(kt*32 + lr)      * EE + kg*32 + lg*8);
            sb1[kg] = *(const short8*)(pb + (size_t)(kt*32 + 16 + lr) * EE + kg*32 + lg*8);
        }
        f32x4 sc0 = {0.f,0.f,0.f,0.f}, sc1 = {0.f,0.f,0.f,0.f};
        #pragma unroll
        for (int kg = 0; kg < 8; ++kg) {
            sc0 = mfma16(qf[kg], sb0[kg], sc0);
            sc1 = mfma16(qf[kg], sb1[kg], sc1);
        }
        short8 pvb[16];
        #pragma unroll
        for (int nt = 0; nt < 16; ++nt)
            pvb[nt] = *(const short8*)(pbT + (size_t)(nt*16 + lr) * SS + kt*32 + lg*8);

        #pragma unroll
        for (int r = 0; r < 4; ++r) {
            float s0 = sc0[r] * scale, s1 = sc1[r] * scale;
            float tm = fmaxf(s0, s1);
            tm = fmaxf(tm, __shfl_xor(tm, 1));
            tm = fmaxf(tm, __shfl_xor(tm, 2));
            tm = fmaxf(tm, __shfl_xor(tm, 4));
            tm = fmaxf(tm, __shfl_xor(tm, 8));
            float mn = fmaxf(m[r], tm);
            float rs = __expf(m[r] - mn);
            m[r] = mn;
            float p0 = __expf(s0 - mn), p1 = __expf(s1 - mn);
            float psum = p0 + p1;
            psum += __shfl_xor(psum, 1);
            psum += __shfl_xor(psum, 2);
            psum += __shfl_xor(psum, 4);
            psum += __shfl_xor(psum, 8);
            ls[r] = ls[r] * rs + psum;
            #pragma unroll
            for (int nt = 0; nt < 16; ++nt) acc[nt][r] *= rs;
            int q = lg * 4 + r;
            wl[q * 40 + lr]      = f2bf(p0);
            wl[q * 40 + 16 + lr] = f2bf(p1);
        }
        short8 pa = *(const short8*)(wl + lr * 40 + lg * 8);
        #pragma unroll
        for (int nt = 0; nt < 16; ++nt)
            acc[nt] = mfma16(pa, pvb[nt], acc[nt]);
    }

    #pragma unroll
    for (int nt = 0; nt < 16; ++nt)
        #pragma unroll
        for (int r = 0; r < 4; ++r)
            accL[w][lg * 4 + r][nt * 16 + lr] = acc[nt][r];
    if (lr == 0) {
        #pragma unroll
        for (int r = 0; r < 4; ++r) {
            mL[w][lg * 4 + r]  = m[r];
            lsL[w][lg * 4 + r] = ls[r];
        }
    }
    __syncthreads();

    const int q = tid >> 4, c = tid & 15;
    float M = fmaxf(fmaxf(mL[0][q], mL[1][q]), fmaxf(mL[2][q], mL[3][q]));
    float sc[4], L = 0.f;
    #pragma unroll
    for (int w2 = 0; w2 < 4; ++w2) {
        sc[w2] = __expf(mL[w2][q] - M);
        L += lsL[w2][q] * sc[w2];
    }
    float inv = 1.0f / L;
    short ov[16];
    #pragma unroll
    for (int j = 0; j < 4; ++j) {
        float4 v = {0.f, 0.f, 0.f, 0.f};
        #pragma unroll
        for (int w2 = 0; w2 < 4; ++w2) {
            float4 a = *(const float4*)&accL[w2][q][c * 16 + j * 4];
            v.x += a.x * sc[w2]; v.y += a.y * sc[w2];
            v.z += a.z * sc[w2]; v.w += a.w * sc[w2];
        }
        ov[j*4 + 0] = f2bf(v.x * inv);
        ov[j*4 + 1] = f2bf(v.y * inv);
        ov[j*4 + 2] = f2bf(v.z * inv);
        ov[j*4 + 3] = f2bf(v.w * inv);
    }
    short* yr = ybf + ((size_t)b * SS + q0 + q) * EE + c * 16;
    *(short8*)yr       = *(const short8*)&ov[0];
    *(short8*)(yr + 8) = *(const short8*)&ov[8];
}

// ---------------------------------------------------------------------------
// Kernel 4: x = LN(x + y@Wc + bc). Unchanged.
// ---------------------------------------------------------------------------
__global__ __launch_bounds__(256) void k_wc3(
        const short* __restrict__ ybf, const short* __restrict__ WcT,
        const float* __restrict__ bc, const float* __restrict__ g,
        const float* __restrict__ bn, float* __restrict__ x) {
    const int t = threadIdx.x, w = t >> 6, l = t & 63;
    const int lr = l & 15, lg = l >> 4;
    const int tok0 = blockIdx.x * 16;
    __shared__ float outl[16 * 260];

    short8 af[8];
    #pragma unroll
    for (int kg = 0; kg < 8; ++kg)
        af[kg] = *(const short8*)(ybf + (size_t)(tok0 + lr) * EE + kg*32 + lg*8);

    f32x4 acc[4];
    #pragma unroll
    for (int i = 0; i < 4; ++i) acc[i] = f32x4{0.f,0.f,0.f,0.f};
    #pragma unroll
    for (int nt = 0; nt < 4; ++nt) {
        int e = w * 64 + nt * 16 + lr;
        #pragma unroll
        for (int kg = 0; kg < 8; ++kg) {
            short8 bv = *(const short8*)(WcT + (size_t)e * EE + kg*32 + lg*8);
            acc[nt] = mfma16(af[kg], bv, acc[nt]);
        }
    }
    #pragma unroll
    for (int nt = 0; nt < 4; ++nt) {
        int e = w * 64 + nt * 16 + lr;
        float bce = bc[e];
        #pragma unroll
        for (int r = 0; r < 4; ++r)
            outl[(lg*4 + r) * 260 + e] = acc[nt][r] + bce;
    }
    __syncthreads();
    #pragma unroll
    for (int j = 0; j < 4; ++j) {
        int q = w * 4 + j;
        float4 v  = *(float4*)&outl[q * 260 + l * 4];
        float4 xv = *(float4*)(x + (size_t)(tok0 + q) * EE + l * 4);
        v.x += xv.x; v.y += xv.y; v.z += xv.z; v.w += xv.w;
        float s = v.x + v.y + v.z + v.w;
        for (int off = 32; off > 0; off >>= 1) s += __shfl_xor(s, off);
        float mean = s * (1.0f / EE);
        float4 d;
        d.x = v.x - mean; d.y = v.y - mean; d.z = v.z - mean; d.w = v.w - mean;
        float s2 = d.x*d.x + d.y*d.y + d.z*d.z + d.w*d.w;
        for (int off = 32; off > 0; off >>= 1) s2 += __shfl_xor(s2, off);
        float inv = rsqrtf(s2 * (1.0f / EE) + 1e-5f);
        float4 gv  = *(const float4*)(g  + l * 4);
        float4 bnv = *(const float4*)(bn + l * 4);
        float4 o;
        o.x = d.x * inv * gv.x + bnv.x;
        o.y = d.y * inv * gv.y + bnv.y;
        o.z = d.z * inv * gv.z + bnv.z;
        o.w = d.w * inv * gv.w + bnv.w;
        *(float4*)(x + (size_t)(tok0 + q) * EE + l * 4) = o;
    }
}

// ---------------------------------------------------------------------------
// Kernel 5: FFN MFMA v4. 32 tokens/block, 512 threads (8 waves), 256 blocks.
// Wave (wg = w>>2, wn = w&3): GEMM1 tokens wg*16..+15, f-slice wn*256..+255,
// in 4 reg-groups of 4 frags (NO runtime-indexed arrays -> no scratch).
// hls [32][1024] bf16 swizzled; outl (fp32 LN buffer) OVERLAYS hls.
// LDS = 16KB qls + 64KB hls = 80KB -> 2 blocks/CU.
// ---------------------------------------------------------------------------
__global__ __launch_bounds__(512) void k_ffn4(
        const float* __restrict__ theta, const short* __restrict__ W1T,
        const float* __restrict__ b1, const short* __restrict__ W2T,
        const float* __restrict__ b2, const float* __restrict__ g,
        const float* __restrict__ bn, float* __restrict__ x) {
    const int t = threadIdx.x, w = t >> 6, l = t & 63;
    const int lr = l & 15, lg = l >> 4;
    const int wg = w >> 2, wn = w & 3;
    const int tok0 = blockIdx.x * 32;

    __shared__ __align__(16) char smem[16384 + 65536];
    char*  qls  = smem;                       // 32x256 bf16, swizzled
    char*  hls  = smem + 16384;               // 32x1024 bf16, swizzled
    float* outl = (float*)(smem + 16384);     // 32x260 f32, overlays hls

    {   // stage qv = cos(x)*cos(theta), bf16, swizzled
        int r = t >> 4, c0 = (t & 15) * 16;
        const float* xr = x + (size_t)(tok0 + r) * EE + c0;
        #pragma unroll
        for (int i = 0; i < 16; i += 2) {
            float v0 = __cosf(xr[i])     * __cosf(theta[c0 + i]);
            float v1 = __cosf(xr[i + 1]) * __cosf(theta[c0 + i + 1]);
            unsigned u = (unsigned)(unsigned short)f2bf(v0) |
                         ((unsigned)(unsigned short)f2bf(v1) << 16);
            int byte = (r * 512 + (c0 + i) * 2) ^ ((r & 7) << 4);
            *(unsigned*)(qls + byte) = u;
        }
    }
    __syncthreads();

    const int qrow = wg * 16 + lr;
    short8 af[8];
    #pragma unroll
    for (int kg = 0; kg < 8; ++kg) {
        int byte = (qrow * 512 + (kg*32 + lg*8) * 2) ^ ((qrow & 7) << 4);
        af[kg] = *(const short8*)(qls + byte);
    }

    // GEMM1: h[wg-tokens][wn*256..+255] in 4 groups of 4 fragments
    for (int gq = 0; gq < 4; ++gq) {
        const int fb = wn * 256 + gq * 64;
        f32x4 a1[4];
        #pragma unroll
        for (int i = 0; i < 4; ++i) a1[i] = f32x4{0.f,0.f,0.f,0.f};
        #pragma unroll
        for (int kg = 0; kg < 8; ++kg) {
            #pragma unroll
            for (int i = 0; i < 4; ++i) {
                short8 bv = *(const short8*)(W1T + (size_t)(fb + i*16 + lr) * NQQ + kg*32 + lg*8);
                a1[i] = mfma16(af[kg], bv, a1[i]);
            }
        }
        #pragma unroll
        for (int i = 0; i < 4; ++i) {
            int f = fb + i * 16 + lr;
            float bb = b1[f];
            #pragma unroll
            for (int r = 0; r < 4; ++r) {
                int q = wg * 16 + lg * 4 + r;
                float hv = fmaxf(a1[i][r] + bb, 0.0f);
                int byte = (q * 2048 + f * 2) ^ ((q & 7) << 4);
                *(short*)(hls + byte) = f2bf(hv);
            }
        }
    }
    __syncthreads();

    // GEMM2: out[wg-tokens][wn*64..+63], K=1024
    f32x4 a2[4];
    #pragma unroll
    for (int i = 0; i < 4; ++i) a2[i] = f32x4{0.f,0.f,0.f,0.f};
    for (int kg = 0; kg < 32; ++kg) {
        int byte = (qrow * 2048 + (kg*32 + lg*8) * 2) ^ ((qrow & 7) << 4);
        short8 hf = *(const short8*)(hls + byte);
        #pragma unroll
        for (int nt = 0; nt < 4; ++nt) {
            int e = wn * 64 + nt * 16 + lr;
            short8 bv = *(const short8*)(W2T + (size_t)e * FF + kg*32 + lg*8);
            a2[nt] = mfma16(hf, bv, a2[nt]);
        }
    }
    __syncthreads();   // all GEMM2 hls reads done before outl overlays it

    #pragma unroll
    for (int nt = 0; nt < 4; ++nt) {
        int e = wn * 64 + nt * 16 + lr;
        float b2e = b2[e];
        #pragma unroll
        for (int r = 0; r < 4; ++r)
            outl[(wg * 16 + lg * 4 + r) * 260 + e] = a2[nt][r] + b2e;
    }
    __syncthreads();

    // epilogue: residual + LN, wave handles tokens w*4..w*4+3
    #pragma unroll
    for (int j = 0; j < 4; ++j) {
        int q = w * 4 + j;
        float4 v  = *(float4*)&outl[q * 260 + l * 4];
        float4 xv = *(float4*)(x + (size_t)(tok0 + q) * EE + l * 4);
        v.x += xv.x; v.y += xv.y; v.z += xv.z; v.w += xv.w;
        float s = v.x + v.y + v.z + v.w;
        for (int off = 32; off > 0; off >>= 1) s += __shfl_xor(s, off);
        float mean = s * (1.0f / EE);
        float4 d;
        d.x = v.x - mean; d.y = v.y - mean; d.z = v.z - mean; d.w = v.w - mean;
        float s2 = d.x*d.x + d.y*d.y + d.z*d.z + d.w*d.w;
        for (int off = 32; off > 0; off >>= 1) s2 += __shfl_xor(s2, off);
        float inv = rsqrtf(s2 * (1.0f / EE) + 1e-5f);
        float4 gv  = *(const float4*)(g  + l * 4);
        float4 bnv = *(const float4*)(bn + l * 4);
        float4 o;
        o.x = d.x * inv * gv.x + bnv.x;
        o.y = d.y * inv * gv.y + bnv.y;
        o.z = d.z * inv * gv.z + bnv.z;
        o.w = d.w * inv * gv.w + bnv.w;
        *(float4*)(x + (size_t)(tok0 + q) * EE + l * 4) = o;
    }
}

// ---------------------------------------------------------------------------
// Kernel 6: classifier head
// ---------------------------------------------------------------------------
__global__ void k_head(const float* __restrict__ x,
                       const float* __restrict__ Wcls,
                       const float* __restrict__ bcls,
                       float* __restrict__ out) {
    int b = blockIdx.x;
    int t = threadIdx.x;
    __shared__ float xm[EE];
    float acc = 0.0f;
    for (int s = 0; s < SS; ++s) acc += x[(size_t)(b * SS + s) * EE + t];
    xm[t] = acc * (1.0f / (float)SS);
    __syncthreads();
    if (t < CC) {
        float a = bcls[t];
        #pragma unroll 8
        for (int e = 0; e < EE; ++e) a += xm[e] * Wcls[e * CC + t];
        out[b * CC + t] = a;
    }
}

// ---------------------------------------------------------------------------
extern "C" void kernel_launch(void* const* d_in, const int* in_sizes, int n_in,
                              void* d_out, int out_size, void* d_ws, size_t ws_size,
                              hipStream_t stream) {
    (void)in_sizes; (void)n_in; (void)out_size; (void)ws_size;
    const int*   tokens     = (const int*)d_in[0];
    const float* emb        = (const float*)d_in[1];
    const float* theta_attn = (const float*)d_in[2];
    const float* Wc         = (const float*)d_in[3];
    const float* bc         = (const float*)d_in[4];
    const float* g1         = (const float*)d_in[5];
    const float* bn1        = (const float*)d_in[6];
    const float* theta_ffn  = (const float*)d_in[7];
    const float* W1         = (const float*)d_in[8];
    const float* b1         = (const float*)d_in[9];
    const float* W2         = (const float*)d_in[10];
    const float* b2         = (const float*)d_in[11];
    const float* g2         = (const float*)d_in[12];
    const float* bn2        = (const float*)d_in[13];
    const float* Wcls       = (const float*)d_in[14];
    const float* bcls       = (const float*)d_in[15];
    float* out = (float*)d_out;

    const size_t nTok = (size_t)BB * SS * EE;     // 2M
    float* x    = (float*)d_ws;                   // 8 MB
    short* pbf  = (short*)(x + nTok);             // 4 MB
    short* pbfT = pbf  + nTok;                    // 4 MB
    short* ybf  = pbfT + nTok;                    // 4 MB
    short* W1T  = ybf  + nTok;                    // 2 MB
    short* W2T  = W1T + (size_t)LL * FF * NQQ;    // 2 MB
    short* WcT  = W2T + (size_t)LL * EE * FF;     // 0.5 MB

    k_embed<<<BB * SS, EE, 0, stream>>>(tokens, emb, x);
    k_trall<<<LL * 576, 256, 0, stream>>>(W1, W2, Wc, W1T, W2T, WcT);

    for (int l = 0; l < LL; ++l) {
        k_qproj2<<<(BB * SS * HH) / 256, 256, 0, stream>>>(
            x, theta_attn + (size_t)l * HH * DKK, pbf, pbfT);
        k_attn4<<<BB * 64, 256, 0, stream>>>(pbf, pbfT, ybf);
        k_wc3<<<(BB * SS) / 16, 256, 0, stream>>>(
            ybf, WcT + (size_t)l * EE * EE, bc + (size_t)l * EE,
            g1 + (size_t)l * EE, bn1 + (size_t)l * EE, x);
        k_ffn4<<<(BB * SS) / 32, 512, 0, stream>>>(
            theta_ffn + (size_t)l * NQQ,
            W1T + (size_t)l * FF * NQQ, b1 + (size_t)l * FF,
            W2T + (size_t)l * EE * FF, b2 + (size_t)l * EE,
            g2 + (size_t)l * EE, bn2 + (size_t)l * EE, x);
    }

    k_head<<<BB, 256, 0, stream>>>(x, Wcls, bcls, out);
}

// Round 6
// 435.382 us; speedup vs baseline: 1.5690x; 1.5690x over previous
//
#include <hip/hip_runtime.h>
#include <hip/hip_bf16.h>
#include <math.h>

#define BB 8
#define SS 1024
#define EE 256
#define HH 8
#define DKK 32
#define LL 4
#define FF 1024
#define NQQ 256
#define CC 10

typedef __attribute__((ext_vector_type(8))) short short8;
typedef __attribute__((ext_vector_type(4))) short s16x4;
typedef __attribute__((ext_vector_type(4))) float f32x4;

static __device__ __forceinline__ f32x4 mfma16(short8 a, short8 b, f32x4 c) {
    return __builtin_amdgcn_mfma_f32_16x16x32_bf16(a, b, c, 0, 0, 0);
}
static __device__ __forceinline__ short f2bf(float f) {
    __hip_bfloat16 h = __float2bfloat16(f);
    return *reinterpret_cast<short*>(&h);
}

// Fragment-packed layout: P[(tile*KG + kg)*64 + lane] (short8 units).
// Entry (tile,kg,lane=lg*16+lr) holds row=tile*16+lr, cols kg*32+lg*8..+7.
// A lane's 16B load is base + lane*16B -> fully coalesced 1KB per wave.
#define FRAG(P, tile, KG, kg, l) ((P) + (((size_t)((tile)*(KG) + (kg)))*64 + (l))*8)

// ---------------------------------------------------------------------------
// Kernel 1: x[b,s,e] = emb[tokens[b,s], e] + pos_encoding(s, e)  (fp32, exact)
// ---------------------------------------------------------------------------
__global__ void k_embed(const int* __restrict__ tokens,
                        const float* __restrict__ emb,
                        float* __restrict__ x) {
    int bs = blockIdx.x;
    int e  = threadIdx.x;
    int s  = bs & (SS - 1);
    int tok = tokens[bs];
    int i2 = e >> 1;
    float div = expf(-(float)(2 * i2) * (logf(10000.0f) / (float)EE));
    float ang = (float)s * div;
    float pe = (e & 1) ? cosf(ang) : sinf(ang);
    x[bs * EE + e] = emb[tok * EE + e] + pe;
}

// ---------------------------------------------------------------------------
// Prep: transpose+convert weights to bf16, FRAGMENT-PACKED output.
// ---------------------------------------------------------------------------
__global__ __launch_bounds__(256) void k_trall(
        const float* __restrict__ W1, const float* __restrict__ W2,
        const float* __restrict__ Wc,
        short* __restrict__ W1P, short* __restrict__ W2P, short* __restrict__ WcP) {
    int bid = blockIdx.x;
    int lyr = bid / 576, rem = bid % 576;
    const float* in; short* out; int R, C, tile;
    if (rem < 256)      { in = W1 + (size_t)lyr*NQQ*FF; out = W1P + (size_t)lyr*FF*NQQ; R = NQQ; C = FF;  tile = rem; }
    else if (rem < 512) { in = W2 + (size_t)lyr*FF*EE;  out = W2P + (size_t)lyr*EE*FF;  R = FF;  C = EE;  tile = rem - 256; }
    else                { in = Wc + (size_t)lyr*EE*EE;  out = WcP + (size_t)lyr*EE*EE;  R = EE;  C = EE;  tile = rem - 512; }
    const int KG = R >> 5;           // K-chunks of 32
    int tiles_c = C >> 5;
    int tc = tile % tiles_c, tr = tile / tiles_c;
    __shared__ float tl[32][33];
    int t = threadIdx.x;
    int rr = t >> 5, cc = t & 31;
    #pragma unroll
    for (int i = 0; i < 4; ++i)
        tl[rr + i*8][cc] = in[(size_t)(tr*32 + rr + i*8) * C + tc*32 + cc];
    __syncthreads();
    int ro = t >> 3, co = (t & 7) * 4;
    int n = tc*32 + ro;              // N index (output row)
    int k = tr*32 + co;              // K index
    int ntile = n >> 4, lr = n & 15;
    int kg = k >> 5, lg = (k & 31) >> 3, j0 = k & 7;   // j0 in {0,4}
    s16x4 v;
    v[0] = f2bf(tl[co + 0][ro]);
    v[1] = f2bf(tl[co + 1][ro]);
    v[2] = f2bf(tl[co + 2][ro]);
    v[3] = f2bf(tl[co + 3][ro]);
    *(s16x4*)(FRAG(out, ntile, KG, kg, lg*16 + lr) + j0) = v;
}

// ---------------------------------------------------------------------------
// Kernel 2: quantum projection -> PQ (packed, rows=s, cols=e; serves Q-A-frags
// and K-B-frags) and PT (packed, rows=e, cols=s; serves PV B-frags).
// One thread per (b,s,h).
// ---------------------------------------------------------------------------
__global__ __launch_bounds__(256) void k_qproj2(
        const float* __restrict__ x, const float* __restrict__ theta,
        short* __restrict__ PQ, short* __restrict__ PT) {
    int idx = blockIdx.x * 256 + threadIdx.x;
    int h  = idx & (HH - 1);
    int bs = idx >> 3;
    int b  = bs >> 10, s = bs & (SS - 1);
    const float* xr = x + (size_t)bs * EE + h * DKK;
    const float* th = theta + h * DKK;
    float v[DKK];
    float cum = __cosf(xr[0] + th[0]);
    float prod1 = 1.0f;
    #pragma unroll
    for (int j = 1; j < DKK; ++j) {
        float c = __cosf(xr[j] + th[j]);
        cum *= c;
        prod1 *= c;
        v[j] = cum;
    }
    v[0] = prod1;

    // PQ: tile = s>>4 (64/b), KG = 8, kg = h, lane = lg*16 + (s&15)
    short* pq = PQ + (size_t)b * SS * EE;
    int stile = s >> 4, lr = s & 15;
    #pragma unroll
    for (int lg = 0; lg < 4; ++lg) {
        short8 u;
        #pragma unroll
        for (int j = 0; j < 8; ++j) u[j] = f2bf(v[lg*8 + j]);
        *(short8*)FRAG(pq, stile*8 + h, 1, 0, lg*16 + lr) = u;
    }

    // PT: tile = e>>4 (16/b), KG = 32, kg = s>>5, lane = ((s>>3)&3)*16 + (e&15)
    short* pt = PT + (size_t)b * SS * EE;
    int kt = s >> 5, lgs = (s >> 3) & 3, j0 = s & 7;
    #pragma unroll
    for (int j = 0; j < 32; ++j) {
        int e = h * 32 + j;
        FRAG(pt, e >> 4, 32, kt, lgs*16 + (e & 15))[j0] = f2bf(v[j]);
    }
}

// ---------------------------------------------------------------------------
// Kernel 3: flash attention, MFMA bf16, KV-split over 4 waves, packed I/O.
// grid = B*64 blocks, 256 threads.
// ---------------------------------------------------------------------------
__global__ __launch_bounds__(256) void k_attn4(const short* __restrict__ PQ,
                                               const short* __restrict__ PT,
                                               short* __restrict__ YP) {
    const int b   = blockIdx.x >> 6;
    const int qt  = blockIdx.x & 63;
    const int tid = threadIdx.x;
    const int w   = tid >> 6;
    const int l   = tid & 63;
    const int lr  = l & 15, lg = l >> 4;
    const short* pq = PQ + (size_t)b * SS * EE;
    const short* pt = PT + (size_t)b * SS * EE;

    __shared__ float accL[4][16][264];
    __shared__ float mL[4][16];
    __shared__ float lsL[4][16];
    __shared__ short wlds[4][16 * 40];

    short8 qf[8];
    #pragma unroll
    for (int kg = 0; kg < 8; ++kg)
        qf[kg] = *(const short8*)FRAG(pq, qt*8 + kg, 1, 0, l);

    f32x4 acc[16];
    #pragma unroll
    for (int i = 0; i < 16; ++i) acc[i] = f32x4{0.f, 0.f, 0.f, 0.f};
    float m[4]  = {-1e30f, -1e30f, -1e30f, -1e30f};
    float ls[4] = {0.f, 0.f, 0.f, 0.f};
    const float scale = 0.17677669529663687f;   // 1/sqrt(32)
    short* wl = wlds[w];

    for (int i = 0; i < 8; ++i) {
        const int kt = w + 4 * i;
        short8 sb0[8], sb1[8];
        #pragma unroll
        for (int kg = 0; kg < 8; ++kg) {
            sb0[kg] = *(const short8*)FRAG(pq, (2*kt)*8   + kg, 1, 0, l);
            sb1[kg] = *(const short8*)FRAG(pq, (2*kt+1)*8 + kg, 1, 0, l);
        }
        f32x4 sc0 = {0.f,0.f,0.f,0.f}, sc1 = {0.f,0.f,0.f,0.f};
        #pragma unroll
        for (int kg = 0; kg < 8; ++kg) {
            sc0 = mfma16(qf[kg], sb0[kg], sc0);
            sc1 = mfma16(qf[kg], sb1[kg], sc1);
        }
        short8 pvb[16];
        #pragma unroll
        for (int nt = 0; nt < 16; ++nt)
            pvb[nt] = *(const short8*)FRAG(pt, nt, 32, kt, l);

        #pragma unroll
        for (int r = 0; r < 4; ++r) {
            float s0 = sc0[r] * scale, s1 = sc1[r] * scale;
            float tm = fmaxf(s0, s1);
            tm = fmaxf(tm, __shfl_xor(tm, 1));
            tm = fmaxf(tm, __shfl_xor(tm, 2));
            tm = fmaxf(tm, __shfl_xor(tm, 4));
            tm = fmaxf(tm, __shfl_xor(tm, 8));
            float mn = fmaxf(m[r], tm);
            float rs = __expf(m[r] - mn);
            m[r] = mn;
            float p0 = __expf(s0 - mn), p1 = __expf(s1 - mn);
            float psum = p0 + p1;
            psum += __shfl_xor(psum, 1);
            psum += __shfl_xor(psum, 2);
            psum += __shfl_xor(psum, 4);
            psum += __shfl_xor(psum, 8);
            ls[r] = ls[r] * rs + psum;
            #pragma unroll
            for (int nt = 0; nt < 16; ++nt) acc[nt][r] *= rs;
            int q = lg * 4 + r;
            wl[q * 40 + lr]      = f2bf(p0);
            wl[q * 40 + 16 + lr] = f2bf(p1);
        }
        short8 pa = *(const short8*)(wl + lr * 40 + lg * 8);
        #pragma unroll
        for (int nt = 0; nt < 16; ++nt)
            acc[nt] = mfma16(pa, pvb[nt], acc[nt]);
    }

    #pragma unroll
    for (int nt = 0; nt < 16; ++nt)
        #pragma unroll
        for (int r = 0; r < 4; ++r)
            accL[w][lg * 4 + r][nt * 16 + lr] = acc[nt][r];
    if (lr == 0) {
        #pragma unroll
        for (int r = 0; r < 4; ++r) {
            mL[w][lg * 4 + r]  = m[r];
            lsL[w][lg * 4 + r] = ls[r];
        }
    }
    __syncthreads();

    // merge: thread -> (q = tid>>4, cols c*16..+15); write YP packed
    const int q = tid >> 4, c = tid & 15;
    float M = fmaxf(fmaxf(mL[0][q], mL[1][q]), fmaxf(mL[2][q], mL[3][q]));
    float sc[4], L = 0.f;
    #pragma unroll
    for (int w2 = 0; w2 < 4; ++w2) {
        sc[w2] = __expf(mL[w2][q] - M);
        L += lsL[w2][q] * sc[w2];
    }
    float inv = 1.0f / L;
    short ov[16];
    #pragma unroll
    for (int j = 0; j < 4; ++j) {
        float4 v = {0.f, 0.f, 0.f, 0.f};
        #pragma unroll
        for (int w2 = 0; w2 < 4; ++w2) {
            float4 a = *(const float4*)&accL[w2][q][c * 16 + j * 4];
            v.x += a.x * sc[w2]; v.y += a.y * sc[w2];
            v.z += a.z * sc[w2]; v.w += a.w * sc[w2];
        }
        ov[j*4 + 0] = f2bf(v.x * inv);
        ov[j*4 + 1] = f2bf(v.y * inv);
        ov[j*4 + 2] = f2bf(v.z * inv);
        ov[j*4 + 3] = f2bf(v.w * inv);
    }
    short* yb = YP + (size_t)b * SS * EE;
    int kgo = c >> 1, lgo = (c & 1) * 2;
    *(short8*)FRAG(yb, qt*8 + kgo, 1, 0, lgo*16 + q)       = *(const short8*)&ov[0];
    *(short8*)FRAG(yb, qt*8 + kgo, 1, 0, (lgo+1)*16 + q)   = *(const short8*)&ov[8];
}

// ---------------------------------------------------------------------------
// Kernel 4: x = LN(x + y@Wc + bc). Packed A (YP) and B (WcP).
// ---------------------------------------------------------------------------
__global__ __launch_bounds__(256) void k_wc3(
        const short* __restrict__ YP, const short* __restrict__ WcP,
        const float* __restrict__ bc, const float* __restrict__ g,
        const float* __restrict__ bn, float* __restrict__ x) {
    const int t = threadIdx.x, w = t >> 6, l = t & 63;
    const int lr = l & 15, lg = l >> 4;
    const int tok0 = blockIdx.x * 16;
    const int b = blockIdx.x >> 6, qt = blockIdx.x & 63;
    const short* yb = YP + (size_t)b * SS * EE;
    __shared__ float outl[16 * 260];

    short8 af[8];
    #pragma unroll
    for (int kg = 0; kg < 8; ++kg)
        af[kg] = *(const short8*)FRAG(yb, qt*8 + kg, 1, 0, l);

    f32x4 acc[4];
    #pragma unroll
    for (int i = 0; i < 4; ++i) acc[i] = f32x4{0.f,0.f,0.f,0.f};
    #pragma unroll
    for (int nt = 0; nt < 4; ++nt) {
        #pragma unroll
        for (int kg = 0; kg < 8; ++kg) {
            short8 bv = *(const short8*)FRAG(WcP, w*4 + nt, 8, kg, l);
            acc[nt] = mfma16(af[kg], bv, acc[nt]);
        }
    }
    #pragma unroll
    for (int nt = 0; nt < 4; ++nt) {
        int e = w * 64 + nt * 16 + lr;
        float bce = bc[e];
        #pragma unroll
        for (int r = 0; r < 4; ++r)
            outl[(lg*4 + r) * 260 + e] = acc[nt][r] + bce;
    }
    __syncthreads();
    #pragma unroll
    for (int j = 0; j < 4; ++j) {
        int q = w * 4 + j;
        float4 v  = *(float4*)&outl[q * 260 + l * 4];
        float4 xv = *(float4*)(x + (size_t)(tok0 + q) * EE + l * 4);
        v.x += xv.x; v.y += xv.y; v.z += xv.z; v.w += xv.w;
        float s = v.x + v.y + v.z + v.w;
        for (int off = 32; off > 0; off >>= 1) s += __shfl_xor(s, off);
        float mean = s * (1.0f / EE);
        float4 d;
        d.x = v.x - mean; d.y = v.y - mean; d.z = v.z - mean; d.w = v.w - mean;
        float s2 = d.x*d.x + d.y*d.y + d.z*d.z + d.w*d.w;
        for (int off = 32; off > 0; off >>= 1) s2 += __shfl_xor(s2, off);
        float inv = rsqrtf(s2 * (1.0f / EE) + 1e-5f);
        float4 gv  = *(const float4*)(g  + l * 4);
        float4 bnv = *(const float4*)(bn + l * 4);
        float4 o;
        o.x = d.x * inv * gv.x + bnv.x;
        o.y = d.y * inv * gv.y + bnv.y;
        o.z = d.z * inv * gv.z + bnv.z;
        o.w = d.w * inv * gv.w + bnv.w;
        *(float4*)(x + (size_t)(tok0 + q) * EE + l * 4) = o;
    }
}

// ---------------------------------------------------------------------------
// Kernel 5: FFN MFMA v4 with packed weights. 32 tokens/block, 512 threads.
// ---------------------------------------------------------------------------
__global__ __launch_bounds__(512) void k_ffn4(
        const float* __restrict__ theta, const short* __restrict__ W1P,
        const float* __restrict__ b1, const short* __restrict__ W2P,
        const float* __restrict__ b2, const float* __restrict__ g,
        const float* __restrict__ bn, float* __restrict__ x) {
    const int t = threadIdx.x, w = t >> 6, l = t & 63;
    const int lr = l & 15, lg = l >> 4;
    const int wg = w >> 2, wn = w & 3;
    const int tok0 = blockIdx.x * 32;

    __shared__ __align__(16) char smem[16384 + 65536];
    char*  qls  = smem;                       // 32x256 bf16, swizzled
    char*  hls  = smem + 16384;               // 32x1024 bf16, swizzled
    float* outl = (float*)(smem + 16384);     // 32x260 f32, overlays hls

    {   // stage qv = cos(x)*cos(theta), bf16, swizzled (vector x loads)
        int r = t >> 4, c0 = (t & 15) * 16;
        const float4* xr4 = (const float4*)(x + (size_t)(tok0 + r) * EE + c0);
        const float4* th4 = (const float4*)(theta + c0);
        float xv[16], tv[16];
        #pragma unroll
        for (int i4 = 0; i4 < 4; ++i4) {
            *(float4*)&xv[i4*4] = xr4[i4];
            *(float4*)&tv[i4*4] = th4[i4];
        }
        #pragma unroll
        for (int i = 0; i < 16; i += 2) {
            float v0 = __cosf(xv[i])     * __cosf(tv[i]);
            float v1 = __cosf(xv[i + 1]) * __cosf(tv[i + 1]);
            unsigned u = (unsigned)(unsigned short)f2bf(v0) |
                         ((unsigned)(unsigned short)f2bf(v1) << 16);
            int byte = (r * 512 + (c0 + i) * 2) ^ ((r & 7) << 4);
            *(unsigned*)(qls + byte) = u;
        }
    }
    __syncthreads();

    const int qrow = wg * 16 + lr;
    short8 af[8];
    #pragma unroll
    for (int kg = 0; kg < 8; ++kg) {
        int byte = (qrow * 512 + (kg*32 + lg*8) * 2) ^ ((qrow & 7) << 4);
        af[kg] = *(const short8*)(qls + byte);
    }

    // GEMM1: h[wg-tokens][wn*256..+255] in 4 groups of 4 fragments
    for (int gq = 0; gq < 4; ++gq) {
        f32x4 a1[4];
        #pragma unroll
        for (int i = 0; i < 4; ++i) a1[i] = f32x4{0.f,0.f,0.f,0.f};
        #pragma unroll
        for (int kg = 0; kg < 8; ++kg) {
            #pragma unroll
            for (int i = 0; i < 4; ++i) {
                short8 bv = *(const short8*)FRAG(W1P, wn*16 + gq*4 + i, 8, kg, l);
                a1[i] = mfma16(af[kg], bv, a1[i]);
            }
        }
        #pragma unroll
        for (int i = 0; i < 4; ++i) {
            int f = wn * 256 + gq * 64 + i * 16 + lr;
            float bb = b1[f];
            #pragma unroll
            for (int r = 0; r < 4; ++r) {
                int q = wg * 16 + lg * 4 + r;
                float hv = fmaxf(a1[i][r] + bb, 0.0f);
                int byte = (q * 2048 + f * 2) ^ ((q & 7) << 4);
                *(short*)(hls + byte) = f2bf(hv);
            }
        }
    }
    __syncthreads();

    // GEMM2: out[wg-tokens][wn*64..+63], K=1024
    f32x4 a2[4];
    #pragma unroll
    for (int i = 0; i < 4; ++i) a2[i] = f32x4{0.f,0.f,0.f,0.f};
    for (int kg = 0; kg < 32; ++kg) {
        int byte = (qrow * 2048 + (kg*32 + lg*8) * 2) ^ ((qrow & 7) << 4);
        short8 hf = *(const short8*)(hls + byte);
        #pragma unroll
        for (int nt = 0; nt < 4; ++nt) {
            short8 bv = *(const short8*)FRAG(W2P, wn*4 + nt, 32, kg, l);
            a2[nt] = mfma16(hf, bv, a2[nt]);
        }
    }
    __syncthreads();   // all GEMM2 hls reads done before outl overlays it

    #pragma unroll
    for (int nt = 0; nt < 4; ++nt) {
        int e = wn * 64 + nt * 16 + lr;
        float b2e = b2[e];
        #pragma unroll
        for (int r = 0; r < 4; ++r)
            outl[(wg * 16 + lg * 4 + r) * 260 + e] = a2[nt][r] + b2e;
    }
    __syncthreads();

    // epilogue: residual + LN, wave handles tokens w*4..w*4+3
    #pragma unroll
    for (int j = 0; j < 4; ++j) {
        int q = w * 4 + j;
        float4 v  = *(float4*)&outl[q * 260 + l * 4];
        float4 xv = *(float4*)(x + (size_t)(tok0 + q) * EE + l * 4);
        v.x += xv.x; v.y += xv.y; v.z += xv.z; v.w += xv.w;
        float s = v.x + v.y + v.z + v.w;
        for (int off = 32; off > 0; off >>= 1) s += __shfl_xor(s, off);
        float mean = s * (1.0f / EE);
        float4 d;
        d.x = v.x - mean; d.y = v.y - mean; d.z = v.z - mean; d.w = v.w - mean;
        float s2 = d.x*d.x + d.y*d.y + d.z*d.z + d.w*d.w;
        for (int off = 32; off > 0; off >>= 1) s2 += __shfl_xor(s2, off);
        float inv = rsqrtf(s2 * (1.0f / EE) + 1e-5f);
        float4 gv  = *(const float4*)(g  + l * 4);
        float4 bnv = *(const float4*)(bn + l * 4);
        float4 o;
        o.x = d.x * inv * gv.x + bnv.x;
        o.y = d.y * inv * gv.y + bnv.y;
        o.z = d.z * inv * gv.z + bnv.z;
        o.w = d.w * inv * gv.w + bnv.w;
        *(float4*)(x + (size_t)(tok0 + q) * EE + l * 4) = o;
    }
}

// ---------------------------------------------------------------------------
// Kernel 6: classifier head
// ---------------------------------------------------------------------------
__global__ void k_head(const float* __restrict__ x,
                       const float* __restrict__ Wcls,
                       const float* __restrict__ bcls,
                       float* __restrict__ out) {
    int b = blockIdx.x;
    int t = threadIdx.x;
    __shared__ float xm[EE];
    float acc = 0.0f;
    for (int s = 0; s < SS; ++s) acc += x[(size_t)(b * SS + s) * EE + t];
    xm[t] = acc * (1.0f / (float)SS);
    __syncthreads();
    if (t < CC) {
        float a = bcls[t];
        #pragma unroll 8
        for (int e = 0; e < EE; ++e) a += xm[e] * Wcls[e * CC + t];
        out[b * CC + t] = a;
    }
}

// ---------------------------------------------------------------------------
extern "C" void kernel_launch(void* const* d_in, const int* in_sizes, int n_in,
                              void* d_out, int out_size, void* d_ws, size_t ws_size,
                              hipStream_t stream) {
    (void)in_sizes; (void)n_in; (void)out_size; (void)ws_size;
    const int*   tokens     = (const int*)d_in[0];
    const float* emb        = (const float*)d_in[1];
    const float* theta_attn = (const float*)d_in[2];
    const float* Wc         = (const float*)d_in[3];
    const float* bc         = (const float*)d_in[4];
    const float* g1         = (const float*)d_in[5];
    const float* bn1        = (const float*)d_in[6];
    const float* theta_ffn  = (const float*)d_in[7];
    const float* W1         = (const float*)d_in[8];
    const float* b1         = (const float*)d_in[9];
    const float* W2         = (const float*)d_in[10];
    const float* b2         = (const float*)d_in[11];
    const float* g2         = (const float*)d_in[12];
    const float* bn2        = (const float*)d_in[13];
    const float* Wcls       = (const float*)d_in[14];
    const float* bcls       = (const float*)d_in[15];
    float* out = (float*)d_out;

    const size_t nTok = (size_t)BB * SS * EE;     // 2M
    float* x    = (float*)d_ws;                   // 8 MB
    short* PQ   = (short*)(x + nTok);             // 4 MB
    short* PT   = PQ  + nTok;                     // 4 MB
    short* YP   = PT  + nTok;                     // 4 MB
    short* W1P  = YP  + nTok;                     // 2 MB
    short* W2P  = W1P + (size_t)LL * FF * NQQ;    // 2 MB
    short* WcP  = W2P + (size_t)LL * EE * FF;     // 0.5 MB

    k_embed<<<BB * SS, EE, 0, stream>>>(tokens, emb, x);
    k_trall<<<LL * 576, 256, 0, stream>>>(W1, W2, Wc, W1P, W2P, WcP);

    for (int l = 0; l < LL; ++l) {
        k_qproj2<<<(BB * SS * HH) / 256, 256, 0, stream>>>(
            x, theta_attn + (size_t)l * HH * DKK, PQ, PT);
        k_attn4<<<BB * 64, 256, 0, stream>>>(PQ, PT, YP);
        k_wc3<<<(BB * SS) / 16, 256, 0, stream>>>(
            YP, WcP + (size_t)l * EE * EE, bc + (size_t)l * EE,
            g1 + (size_t)l * EE, bn1 + (size_t)l * EE, x);
        k_ffn4<<<(BB * SS) / 32, 512, 0, stream>>>(
            theta_ffn + (size_t)l * NQQ,
            W1P + (size_t)l * FF * NQQ, b1 + (size_t)l * FF,
            W2P + (size_t)l * EE * FF, b2 + (size_t)l * EE,
            g2 + (size_t)l * EE, bn2 + (size_t)l * EE, x);
    }

    k_head<<<BB, 256, 0, stream>>>(x, Wcls, bcls, out);
}